// Round 9
// baseline (557.405 us; speedup 1.0000x reference)
//
#include <hip/hip_runtime.h>

#define N_NODES 50000
#define N_EDGES 800000
#define N_FEAT  128
#define N_HID   64

#define BKT_LOG 9
#define BKT_SZ  512                                  // nodes per bucket
#define NBKT    ((N_NODES + BKT_SZ - 1) / BKT_SZ)    // 98
#define CH      4096                                 // edges per partition block
#define NB1     ((N_EDGES + CH - 1) / CH)            // 196

__device__ inline void fma4(float4& acc, float s, const float4& w) {
    acc.x = fmaf(s, w.x, acc.x);
    acc.y = fmaf(s, w.y, acc.y);
    acc.z = fmaf(s, w.z, acc.z);
    acc.w = fmaf(s, w.w, acc.w);
}

__device__ inline unsigned short f2bf(float f) {          // RNE f32 -> bf16
    unsigned u = __float_as_uint(f);
    u = u + 0x7FFFu + ((u >> 16) & 1u);
    return (unsigned short)(u >> 16);
}
__device__ inline float bf2f(unsigned short v) { return __uint_as_float(((unsigned)v) << 16); }

// ---------- tiled GEMM: o[row][col] = sum_k a[row*K+k] * w[k*64+col], bf16 out ----------
template <int K>
__global__ __launch_bounds__(256) void gemm_tile(const float* __restrict__ a,
                                                 const float* __restrict__ w,
                                                 unsigned short* __restrict__ o) {
    __shared__ float lw[K * N_HID];
    int tid = threadIdx.x;
    for (int idx = tid * 4; idx < K * N_HID; idx += 256 * 4)
        *(float4*)&lw[idx] = *(const float4*)&w[idx];
    __syncthreads();

    int row0 = blockIdx.x * 32 + (tid >> 4) * 2;
    if (row0 >= N_NODES) return;
    bool two = (row0 + 1) < N_NODES;
    int c4 = (tid & 15) * 4;

    const float* a0 = a + (long)row0 * K;
    const float* a1 = two ? (a0 + K) : a0;

    float4 acc0 = make_float4(0.f, 0.f, 0.f, 0.f);
    float4 acc1 = acc0;

#pragma unroll 8
    for (int k4 = 0; k4 < K / 4; ++k4) {
        float4 xa = *(const float4*)(a0 + k4 * 4);
        float4 xb = *(const float4*)(a1 + k4 * 4);
        const float* wk = &lw[(k4 * 4) * N_HID + c4];
        float4 w0 = *(const float4*)(wk);
        float4 w1 = *(const float4*)(wk + N_HID);
        float4 w2 = *(const float4*)(wk + 2 * N_HID);
        float4 w3 = *(const float4*)(wk + 3 * N_HID);
        fma4(acc0, xa.x, w0); fma4(acc1, xb.x, w0);
        fma4(acc0, xa.y, w1); fma4(acc1, xb.y, w1);
        fma4(acc0, xa.z, w2); fma4(acc1, xb.z, w2);
        fma4(acc0, xa.w, w3); fma4(acc1, xb.w, w3);
    }

    unsigned short* op = o + (long)row0 * N_HID + c4;
    *(ushort4*)op = make_ushort4(f2bf(acc0.x), f2bf(acc0.y), f2bf(acc0.z), f2bf(acc0.w));
    if (two)
        *(ushort4*)(op + N_HID) = make_ushort4(f2bf(acc1.x), f2bf(acc1.y), f2bf(acc1.z), f2bf(acc1.w));
}

// ---------- CSR build: decoupled radix partition (NO global atomics) ----------
__global__ __launch_bounds__(256) void binhist(const int* __restrict__ dst,
                                               int* __restrict__ cnt,
                                               int* __restrict__ cnt_t) {
    __shared__ int h[NBKT];
    int t = threadIdx.x;
    if (t < NBKT) h[t] = 0;
    __syncthreads();
    int e0 = blockIdx.x * CH;
    for (int i = t; i < CH; i += 256) {
        int e = e0 + i;
        if (e < N_EDGES) atomicAdd(&h[dst[e] >> BKT_LOG], 1);
    }
    __syncthreads();
    if (t < NBKT) {
        int v = h[t];
        cnt[blockIdx.x * NBKT + t] = v;
        cnt_t[t * NB1 + blockIdx.x] = v;
    }
}

__global__ __launch_bounds__(128) void binscan(const int* __restrict__ cnt_t,
                                               int* __restrict__ off,
                                               int* __restrict__ bstart) {
    __shared__ int tot[128];
    int t = threadIdx.x;
    int s = 0;
    if (t < NBKT) {
        const int4* p = (const int4*)(cnt_t + t * NB1);   // NB1 % 4 == 0
#pragma unroll 7
        for (int q = 0; q < NB1 / 4; ++q) {
            int4 v = p[q];
            s += v.x + v.y + v.z + v.w;
        }
    }
    tot[t] = s;
    __syncthreads();
    for (int o = 1; o < 128; o <<= 1) {
        int u = (t >= o) ? tot[t - o] : 0;
        __syncthreads();
        tot[t] += u;
        __syncthreads();
    }
    int excl = tot[t] - s;
    if (t < NBKT) {
        bstart[t] = excl;
        int run = excl;
        const int* p = cnt_t + t * NB1;
        for (int bdx = 0; bdx < NB1; ++bdx) {
            off[bdx * NBKT + t] = run;
            run += p[bdx];
        }
        if (t == NBKT - 1) bstart[NBKT] = run;   // == N_EDGES
    }
}

__global__ __launch_bounds__(256) void binscatter(const int* __restrict__ src,
                                                  const int* __restrict__ dst,
                                                  const float* __restrict__ ew,
                                                  const int* __restrict__ off,
                                                  uint2* __restrict__ slab) {
    __shared__ int cur[NBKT];
    int t = threadIdx.x;
    if (t < NBKT) cur[t] = off[blockIdx.x * NBKT + t];
    __syncthreads();
    int e0 = blockIdx.x * CH;
    for (int i = t; i < CH; i += 256) {
        int e = e0 + i;
        if (e >= N_EDGES) continue;
        int d = dst[e];
        int bin = d >> BKT_LOG;
        int p = atomicAdd(&cur[bin], 1);
        slab[p] = make_uint2((unsigned)src[e] | ((unsigned)(d & (BKT_SZ - 1)) << 16),
                             __float_as_uint(ew[e]));
    }
}

// phase 4: per-bucket LDS counting sort -> packed 4B edges {src:16 | bf16(w):16} + start[]
__global__ __launch_bounds__(512) void sort_bucket(const uint2* __restrict__ slab,
                                                   const int* __restrict__ bstart,
                                                   unsigned* __restrict__ edges,
                                                   int* __restrict__ start) {
    __shared__ int h[BKT_SZ];
    __shared__ int sc[BKT_SZ];
    int b = blockIdx.x;
    int t = threadIdx.x;
    int base = bstart[b];
    int c = bstart[b + 1] - base;

    h[t] = 0;
    __syncthreads();
    for (int i = t; i < c; i += 512)
        atomicAdd(&h[(slab[base + i].x >> 16) & (BKT_SZ - 1)], 1);
    __syncthreads();
    int v = h[t];
    sc[t] = v;
    __syncthreads();
    for (int o = 1; o < BKT_SZ; o <<= 1) {
        int u = (t >= o) ? sc[t - o] : 0;
        __syncthreads();
        sc[t] += u;
        __syncthreads();
    }
    int excl = sc[t] - v;
    int g = (b << BKT_LOG) + t;
    if (g < N_NODES) start[g] = base + excl;
    if (b == NBKT - 1 && t == 0) start[N_NODES] = N_EDGES;
    h[t] = base + excl;
    __syncthreads();
    for (int i = t; i < c; i += 512) {
        uint2 r = slab[base + i];
        int p = atomicAdd(&h[(r.x >> 16) & (BKT_SZ - 1)], 1);
        edges[p] = (r.x & 0xFFFFu) | ((unsigned)f2bf(__uint_as_float(r.y)) << 16);
    }
}

// ---------- pull aggregation v4: bf16 table + 4B edges, 16 slots/trip ----------
template <bool RELU>
__global__ __launch_bounds__(256) void gcn_agg(const unsigned short* __restrict__ hwb,
                                               const unsigned* __restrict__ edges,
                                               const int* __restrict__ start,
                                               const float* __restrict__ b,
                                               float* __restrict__ o) {
    int n = (blockIdx.x * blockDim.x + threadIdx.x) >> 6;
    if (n >= N_NODES) return;
    int lane = threadIdx.x & 63;
    int es = lane >> 4;            // 0..3
    int f4 = (lane & 15) * 4;      // 0,4,...,60

    int i0 = start[n], i1 = start[n + 1];
    float4 acc = make_float4(0.f, 0.f, 0.f, 0.f);

    for (int base = i0; base < i1; base += 16) {
        int ia = base + es;
        int ib = base + 4 + es;
        int ic = base + 8 + es;
        int id = base + 12 + es;
        float wa = 0.f, wb = 0.f, wc = 0.f, wd = 0.f;
        float4 va = make_float4(0.f, 0.f, 0.f, 0.f);
        float4 vb = va, vc = va, vd = va;
        if (ia < i1) {
            unsigned e = edges[ia];
            wa = __uint_as_float(e & 0xFFFF0000u);
            ushort4 v = *(const ushort4*)&hwb[(long)(e & 0xFFFFu) * N_HID + f4];
            va = make_float4(bf2f(v.x), bf2f(v.y), bf2f(v.z), bf2f(v.w));
        }
        if (ib < i1) {
            unsigned e = edges[ib];
            wb = __uint_as_float(e & 0xFFFF0000u);
            ushort4 v = *(const ushort4*)&hwb[(long)(e & 0xFFFFu) * N_HID + f4];
            vb = make_float4(bf2f(v.x), bf2f(v.y), bf2f(v.z), bf2f(v.w));
        }
        if (ic < i1) {
            unsigned e = edges[ic];
            wc = __uint_as_float(e & 0xFFFF0000u);
            ushort4 v = *(const ushort4*)&hwb[(long)(e & 0xFFFFu) * N_HID + f4];
            vc = make_float4(bf2f(v.x), bf2f(v.y), bf2f(v.z), bf2f(v.w));
        }
        if (id < i1) {
            unsigned e = edges[id];
            wd = __uint_as_float(e & 0xFFFF0000u);
            ushort4 v = *(const ushort4*)&hwb[(long)(e & 0xFFFFu) * N_HID + f4];
            vd = make_float4(bf2f(v.x), bf2f(v.y), bf2f(v.z), bf2f(v.w));
        }
        fma4(acc, wa, va);
        fma4(acc, wb, vb);
        fma4(acc, wc, vc);
        fma4(acc, wd, vd);
    }

    acc.x += __shfl_xor(acc.x, 16); acc.y += __shfl_xor(acc.y, 16);
    acc.z += __shfl_xor(acc.z, 16); acc.w += __shfl_xor(acc.w, 16);
    acc.x += __shfl_xor(acc.x, 32); acc.y += __shfl_xor(acc.y, 32);
    acc.z += __shfl_xor(acc.z, 32); acc.w += __shfl_xor(acc.w, 32);

    if (es == 0) {
        float4 bias = *(const float4*)&b[f4];
        acc.x += bias.x; acc.y += bias.y; acc.z += bias.z; acc.w += bias.w;
        if (RELU) {
            acc.x = fmaxf(acc.x, 0.f); acc.y = fmaxf(acc.y, 0.f);
            acc.z = fmaxf(acc.z, 0.f); acc.w = fmaxf(acc.w, 0.f);
        }
        *(float4*)&o[(long)n * N_HID + f4] = acc;
    }
}

// ================= PROBES (diagnostic only; write scratch) =================
// Each repeats its real counterpart's work REPS times; opaque-zero per rep
// defeats CSE so every rep re-issues the memory traffic.

template <int REPS>
__global__ __launch_bounds__(256) void agg_probe(const unsigned short* __restrict__ hwb,
                                                 const unsigned* __restrict__ edges,
                                                 const int* __restrict__ start,
                                                 const float* __restrict__ b,
                                                 float* __restrict__ o) {
    int n = (blockIdx.x * blockDim.x + threadIdx.x) >> 6;
    if (n >= N_NODES) return;
    int lane = threadIdx.x & 63;
    int es = lane >> 4;
    int f4 = (lane & 15) * 4;
    float4 tot = make_float4(0.f, 0.f, 0.f, 0.f);
    for (int r = 0; r < REPS; ++r) {
        int zr = 0;
        asm volatile("" : "+v"(zr));         // opaque 0: blocks cross-rep CSE
        int i0 = start[n] + zr, i1 = start[n + 1];
        float4 acc = make_float4(0.f, 0.f, 0.f, 0.f);
        for (int base = i0; base < i1; base += 16) {
            int ia = base + es, ib = base + 4 + es, ic = base + 8 + es, id = base + 12 + es;
            float wa = 0.f, wb = 0.f, wc = 0.f, wd = 0.f;
            float4 va = make_float4(0.f, 0.f, 0.f, 0.f);
            float4 vb = va, vc = va, vd = va;
            if (ia < i1) { unsigned e = edges[ia]; wa = __uint_as_float(e & 0xFFFF0000u);
                ushort4 v = *(const ushort4*)&hwb[(long)(e & 0xFFFFu) * N_HID + f4];
                va = make_float4(bf2f(v.x), bf2f(v.y), bf2f(v.z), bf2f(v.w)); }
            if (ib < i1) { unsigned e = edges[ib]; wb = __uint_as_float(e & 0xFFFF0000u);
                ushort4 v = *(const ushort4*)&hwb[(long)(e & 0xFFFFu) * N_HID + f4];
                vb = make_float4(bf2f(v.x), bf2f(v.y), bf2f(v.z), bf2f(v.w)); }
            if (ic < i1) { unsigned e = edges[ic]; wc = __uint_as_float(e & 0xFFFF0000u);
                ushort4 v = *(const ushort4*)&hwb[(long)(e & 0xFFFFu) * N_HID + f4];
                vc = make_float4(bf2f(v.x), bf2f(v.y), bf2f(v.z), bf2f(v.w)); }
            if (id < i1) { unsigned e = edges[id]; wd = __uint_as_float(e & 0xFFFF0000u);
                ushort4 v = *(const ushort4*)&hwb[(long)(e & 0xFFFFu) * N_HID + f4];
                vd = make_float4(bf2f(v.x), bf2f(v.y), bf2f(v.z), bf2f(v.w)); }
            fma4(acc, wa, va); fma4(acc, wb, vb); fma4(acc, wc, vc); fma4(acc, wd, vd);
        }
        tot.x += acc.x; tot.y += acc.y; tot.z += acc.z; tot.w += acc.w;
    }
    tot.x += __shfl_xor(tot.x, 16); tot.y += __shfl_xor(tot.y, 16);
    tot.z += __shfl_xor(tot.z, 16); tot.w += __shfl_xor(tot.w, 16);
    tot.x += __shfl_xor(tot.x, 32); tot.y += __shfl_xor(tot.y, 32);
    tot.z += __shfl_xor(tot.z, 32); tot.w += __shfl_xor(tot.w, 32);
    if (es == 0) {
        tot.x += b[f4];
        *(float4*)&o[(long)n * N_HID + f4] = tot;
    }
}

template <int K, int REPS>
__global__ __launch_bounds__(256) void gemm_probe(const float* __restrict__ a,
                                                  const float* __restrict__ w,
                                                  unsigned short* __restrict__ o) {
    __shared__ float lw[K * N_HID];
    int tid = threadIdx.x;
    for (int idx = tid * 4; idx < K * N_HID; idx += 256 * 4)
        *(float4*)&lw[idx] = *(const float4*)&w[idx];
    __syncthreads();
    int row0 = blockIdx.x * 32 + (tid >> 4) * 2;
    if (row0 >= N_NODES) return;
    bool two = (row0 + 1) < N_NODES;
    int c4 = (tid & 15) * 4;
    float4 acc0 = make_float4(0.f, 0.f, 0.f, 0.f);
    float4 acc1 = acc0;
    for (int r = 0; r < REPS; ++r) {
        int zr = 0;
        asm volatile("" : "+v"(zr));
        const float* a0 = a + (long)row0 * K + zr;
        const float* a1 = two ? (a0 + K) : a0;
#pragma unroll 8
        for (int k4 = 0; k4 < K / 4; ++k4) {
            float4 xa = *(const float4*)(a0 + k4 * 4);
            float4 xb = *(const float4*)(a1 + k4 * 4);
            const float* wk = &lw[(k4 * 4) * N_HID + c4];
            float4 w0 = *(const float4*)(wk);
            float4 w1 = *(const float4*)(wk + N_HID);
            float4 w2 = *(const float4*)(wk + 2 * N_HID);
            float4 w3 = *(const float4*)(wk + 3 * N_HID);
            fma4(acc0, xa.x, w0); fma4(acc1, xb.x, w0);
            fma4(acc0, xa.y, w1); fma4(acc1, xb.y, w1);
            fma4(acc0, xa.z, w2); fma4(acc1, xb.z, w2);
            fma4(acc0, xa.w, w3); fma4(acc1, xb.w, w3);
        }
    }
    unsigned short* op = o + (long)row0 * N_HID + c4;
    *(ushort4*)op = make_ushort4(f2bf(acc0.x), f2bf(acc0.y), f2bf(acc0.z), f2bf(acc0.w));
    if (two)
        *(ushort4*)(op + N_HID) = make_ushort4(f2bf(acc1.x), f2bf(acc1.y), f2bf(acc1.z), f2bf(acc1.w));
}

template <int REPS>
__global__ __launch_bounds__(256) void scat_probe(const int* __restrict__ src,
                                                  const int* __restrict__ dst,
                                                  const float* __restrict__ ew,
                                                  const int* __restrict__ off,
                                                  uint2* __restrict__ slab) {
    __shared__ int cur[NBKT];
    int t = threadIdx.x;
    for (int r = 0; r < REPS; ++r) {
        int zr = 0;
        asm volatile("" : "+v"(zr));
        __syncthreads();
        if (t < NBKT) cur[t] = off[blockIdx.x * NBKT + t];
        __syncthreads();
        int e0 = blockIdx.x * CH + zr;
        for (int i = t; i < CH; i += 256) {
            int e = e0 + i;
            if (e >= N_EDGES) continue;
            int d = dst[e];
            int bin = d >> BKT_LOG;
            int p = atomicAdd(&cur[bin], 1);
            slab[p] = make_uint2((unsigned)src[e] | ((unsigned)(d & (BKT_SZ - 1)) << 16),
                                 __float_as_uint(ew[e]));
        }
    }
}

template <int REPS>
__global__ __launch_bounds__(512) void sort_probe(const uint2* __restrict__ slab,
                                                  const int* __restrict__ bstart,
                                                  unsigned* __restrict__ edges,
                                                  int* __restrict__ start) {
    __shared__ int h[BKT_SZ];
    __shared__ int sc[BKT_SZ];
    int b = blockIdx.x;
    int t = threadIdx.x;
    for (int r = 0; r < REPS; ++r) {
        int zr = 0;
        asm volatile("" : "+v"(zr));
        int base = bstart[b] + zr;
        int c = bstart[b + 1] - base;
        __syncthreads();
        h[t] = 0;
        __syncthreads();
        for (int i = t; i < c; i += 512)
            atomicAdd(&h[(slab[base + i].x >> 16) & (BKT_SZ - 1)], 1);
        __syncthreads();
        int v = h[t];
        sc[t] = v;
        __syncthreads();
        for (int o = 1; o < BKT_SZ; o <<= 1) {
            int u = (t >= o) ? sc[t - o] : 0;
            __syncthreads();
            sc[t] += u;
            __syncthreads();
        }
        int excl = sc[t] - v;
        int g = (b << BKT_LOG) + t;
        if (g < N_NODES) start[g] = base + excl;
        h[t] = base + excl;
        __syncthreads();
        for (int i = t; i < c; i += 512) {
            uint2 rr = slab[base + i];
            int p = atomicAdd(&h[(rr.x >> 16) & (BKT_SZ - 1)], 1);
            edges[p] = (rr.x & 0xFFFFu) | ((unsigned)f2bf(__uint_as_float(rr.y)) << 16);
        }
    }
}

extern "C" void kernel_launch(void* const* d_in, const int* in_sizes, int n_in,
                              void* d_out, int out_size, void* d_ws, size_t ws_size,
                              hipStream_t stream) {
    const float* x  = (const float*)d_in[0];
    const int*   ei = (const int*)d_in[1];   // [2, E] flat: src then dst
    const float* ew = (const float*)d_in[2];
    const float* w1 = (const float*)d_in[3];
    const float* b1 = (const float*)d_in[4];
    const float* w2 = (const float*)d_in[5];
    const float* b2 = (const float*)d_in[6];
    float* out = (float*)d_out;

    const int* src = ei;
    const int* dst = ei + N_EDGES;

    // real workspace (~21 MB)
    char* ws = (char*)d_ws;
    unsigned short* hwb = (unsigned short*)ws;                    // 6.4 MB bf16 table
    uint2* slab   = (uint2*)(ws + (size_t)7 * 1024 * 1024);       // 6.4 MB
    unsigned* edges = (unsigned*)(ws + (size_t)14 * 1024 * 1024); // 3.2 MB packed
    int*   start  = (int*)(ws + (size_t)18 * 1024 * 1024);        // 50001 ints
    int*   bstart = start + N_NODES + 3;                          // 99 ints
    int*   cnt    = bstart + NBKT + 3;                            // NB1*NBKT
    int*   cnt_t  = cnt + NB1 * NBKT;                             // NBKT*NB1
    int*   off    = cnt_t + NBKT * NB1;                           // NB1*NBKT

    // probe scratch (disjoint, far region)
    float* o_s          = (float*)(ws + (size_t)64 * 1024 * 1024);   // 12.8 MB
    unsigned short* g_s = (unsigned short*)(ws + (size_t)80 * 1024 * 1024); // 6.4 MB
    uint2* slab_s       = (uint2*)(ws + (size_t)96 * 1024 * 1024);   // 6.4 MB
    unsigned* edges_s   = (unsigned*)(ws + (size_t)112 * 1024 * 1024); // 3.2 MB
    int* start_s        = (int*)(ws + (size_t)120 * 1024 * 1024);    // 50001 ints

    dim3 blk(256);
    dim3 ngrid((N_NODES * N_HID + 255) / 256);   // 12500 (4 nodes / block)
    dim3 ggrid((N_NODES + 31) / 32);             // 1563

    // ---- build CSR: decoupled counting sort, zero global atomics ----
    binhist<<<NB1, blk, 0, stream>>>(dst, cnt, cnt_t);
    binscan<<<1, 128, 0, stream>>>(cnt_t, off, bstart);
    binscatter<<<NB1, blk, 0, stream>>>(src, dst, ew, off, slab);
    sort_bucket<<<NBKT, 512, 0, stream>>>(slab, bstart, edges, start);

    // ---- layer 1: hwb = bf16(x@w1); h = relu(agg+b1) -> d_out (f32) ----
    gemm_tile<N_FEAT><<<ggrid, blk, 0, stream>>>(x, w1, hwb);
    gcn_agg<true><<<ngrid, blk, 0, stream>>>(hwb, edges, start, b1, out);

    // ---- layer 2: hwb = bf16(h@w2); out = agg + b2 ----
    gemm_tile<N_HID><<<ggrid, blk, 0, stream>>>(out, w2, hwb);
    gcn_agg<false><<<ngrid, blk, 0, stream>>>(hwb, edges, start, b2, out);

    // ---- PROBES (scratch-only; measurement round) ----
    agg_probe<8><<<ngrid, blk, 0, stream>>>(hwb, edges, start, b2, o_s);
    gemm_probe<N_HID, 12><<<ggrid, blk, 0, stream>>>(out, w2, g_s);
    scat_probe<12><<<NB1, blk, 0, stream>>>(src, dst, ew, off, slab_s);
    sort_probe<12><<<NBKT, 512, 0, stream>>>(slab, bstart, edges_s, start_s);
}

// Round 10
// 138.502 us; speedup vs baseline: 4.0245x; 4.0245x over previous
//
#include <hip/hip_runtime.h>

#define N_NODES 50000
#define N_EDGES 800000
#define N_FEAT  128
#define N_HID   64

#define BKT_LOG 9
#define BKT_SZ  512                                  // nodes per bucket
#define NBKT    ((N_NODES + BKT_SZ - 1) / BKT_SZ)    // 98
#define CH      4096                                 // edges per partition block
#define NB1     ((N_EDGES + CH - 1) / CH)            // 196
#define GG      ((N_NODES + 31) / 32)                // 1563 gemm blocks

__device__ inline void fma4(float4& acc, float s, const float4& w) {
    acc.x = fmaf(s, w.x, acc.x);
    acc.y = fmaf(s, w.y, acc.y);
    acc.z = fmaf(s, w.z, acc.z);
    acc.w = fmaf(s, w.w, acc.w);
}

__device__ inline unsigned short f2bf(float f) {          // RNE f32 -> bf16
    unsigned u = __float_as_uint(f);
    u = u + 0x7FFFu + ((u >> 16) & 1u);
    return (unsigned short)(u >> 16);
}
__device__ inline float bf2f(unsigned short v) { return __uint_as_float(((unsigned)v) << 16); }

__device__ inline int wave_incl_scan(int v) {
    int lane = threadIdx.x & 63;
#pragma unroll
    for (int o = 1; o < 64; o <<= 1) {
        int u = __shfl_up(v, o);
        if (lane >= o) v += u;
    }
    return v;
}

// ---------- K1: gemm1 (x@w1 -> bf16 hwb) fused with binhist ----------
__global__ __launch_bounds__(256) void gemm1_hist(const float* __restrict__ a,
                                                  const float* __restrict__ w,
                                                  unsigned short* __restrict__ o,
                                                  const int* __restrict__ dst,
                                                  int* __restrict__ cnt,
                                                  int* __restrict__ cnt_t) {
    int tid = threadIdx.x;
    if (blockIdx.x < NB1) {                      // ---- histogram part ----
        __shared__ int h[NBKT];
        int bid = blockIdx.x;
        if (tid < NBKT) h[tid] = 0;
        __syncthreads();
        int e0 = bid * CH;
        for (int i = tid; i < CH; i += 256) {
            int e = e0 + i;
            if (e < N_EDGES) atomicAdd(&h[dst[e] >> BKT_LOG], 1);
        }
        __syncthreads();
        if (tid < NBKT) {
            int v = h[tid];
            cnt[bid * NBKT + tid] = v;
            cnt_t[tid * NB1 + bid] = v;
        }
        return;
    }
    // ---- gemm part ----
    __shared__ float lw[N_FEAT * N_HID];
    for (int idx = tid * 4; idx < N_FEAT * N_HID; idx += 256 * 4)
        *(float4*)&lw[idx] = *(const float4*)&w[idx];
    __syncthreads();

    int blk = blockIdx.x - NB1;
    int row0 = blk * 32 + (tid >> 4) * 2;
    if (row0 >= N_NODES) return;
    bool two = (row0 + 1) < N_NODES;
    int c4 = (tid & 15) * 4;

    const float* a0 = a + (long)row0 * N_FEAT;
    const float* a1 = two ? (a0 + N_FEAT) : a0;

    float4 acc0 = make_float4(0.f, 0.f, 0.f, 0.f);
    float4 acc1 = acc0;

#pragma unroll 8
    for (int k4 = 0; k4 < N_FEAT / 4; ++k4) {
        float4 xa = *(const float4*)(a0 + k4 * 4);
        float4 xb = *(const float4*)(a1 + k4 * 4);
        const float* wk = &lw[(k4 * 4) * N_HID + c4];
        float4 w0 = *(const float4*)(wk);
        float4 w1 = *(const float4*)(wk + N_HID);
        float4 w2 = *(const float4*)(wk + 2 * N_HID);
        float4 w3 = *(const float4*)(wk + 3 * N_HID);
        fma4(acc0, xa.x, w0); fma4(acc1, xb.x, w0);
        fma4(acc0, xa.y, w1); fma4(acc1, xb.y, w1);
        fma4(acc0, xa.z, w2); fma4(acc1, xb.z, w2);
        fma4(acc0, xa.w, w3); fma4(acc1, xb.w, w3);
    }

    unsigned short* op = o + (long)row0 * N_HID + c4;
    *(ushort4*)op = make_ushort4(f2bf(acc0.x), f2bf(acc0.y), f2bf(acc0.z), f2bf(acc0.w));
    if (two)
        *(ushort4*)(op + N_HID) = make_ushort4(f2bf(acc1.x), f2bf(acc1.y), f2bf(acc1.z), f2bf(acc1.w));
}

// ---------- K2: binscatter, self-computing cursor bases (no binscan pass) ----------
__global__ __launch_bounds__(256) void binscatter(const int* __restrict__ src,
                                                  const int* __restrict__ dst,
                                                  const float* __restrict__ ew,
                                                  const int* __restrict__ cnt,
                                                  const int* __restrict__ cnt_t,
                                                  uint2* __restrict__ slab) {
    __shared__ int cur[NBKT];
    __shared__ int wtot[2];
    int t = threadIdx.x;
    int b = blockIdx.x;

    int tot = 0, pre = 0;
    if (t < NBKT) {
        const int4* p = (const int4*)(cnt_t + t * NB1);   // NB1 % 4 == 0
        for (int q = 0; q < NB1 / 4; ++q) {
            int4 v = p[q];
            tot += v.x + v.y + v.z + v.w;
        }
        int p0 = 0, p1 = 0, p2 = 0, p3 = 0;
        int j = 0;
        for (; j + 4 <= b; j += 4) {
            p0 += cnt[(j + 0) * NBKT + t];
            p1 += cnt[(j + 1) * NBKT + t];
            p2 += cnt[(j + 2) * NBKT + t];
            p3 += cnt[(j + 3) * NBKT + t];
        }
        for (; j < b; ++j) p0 += cnt[j * NBKT + t];
        pre = p0 + p1 + p2 + p3;
    }
    int incl = wave_incl_scan(tot);                   // waves 0,1 cover t<98
    if (t < 128 && (t & 63) == 63) wtot[t >> 6] = incl;
    __syncthreads();
    if (t < NBKT) {
        int bstart_t = (t >= 64 ? wtot[0] : 0) + incl - tot;  // exclusive prefix
        cur[t] = bstart_t + pre;
    }
    __syncthreads();

    int e0 = b * CH;
    for (int i = t; i < CH; i += 256) {
        int e = e0 + i;
        if (e >= N_EDGES) continue;
        int d = dst[e];
        int bin = d >> BKT_LOG;
        int p = atomicAdd(&cur[bin], 1);
        slab[p] = make_uint2((unsigned)src[e] | ((unsigned)(d & (BKT_SZ - 1)) << 16),
                             __float_as_uint(ew[e]));
    }
}

// ---------- K3: per-bucket counting sort (self-computed bstart, wave scans) ----------
__global__ __launch_bounds__(512) void sort_bucket(const uint2* __restrict__ slab,
                                                   const int* __restrict__ cnt_t,
                                                   unsigned* __restrict__ edges,
                                                   int* __restrict__ start) {
    __shared__ int tt[NBKT];
    __shared__ int h[BKT_SZ];
    __shared__ int wtot[8];
    __shared__ int bs[2];
    int b = blockIdx.x;
    int t = threadIdx.x;
    int lane = t & 63;
    int w = t >> 6;

    // bucket totals
    if (t < NBKT) {
        int s = 0;
        const int4* p = (const int4*)(cnt_t + t * NB1);
        for (int q = 0; q < NB1 / 4; ++q) {
            int4 v = p[q];
            s += v.x + v.y + v.z + v.w;
        }
        tt[t] = s;
    }
    __syncthreads();
    if (t < 64) {
        int v = (t < b ? tt[t] : 0) + (t + 64 < b ? tt[t + 64] : 0);
#pragma unroll
        for (int o = 32; o >= 1; o >>= 1) v += __shfl_xor(v, o);
        if (t == 0) { bs[0] = v; bs[1] = tt[b]; }
    }
    __syncthreads();
    int base = bs[0];
    int c = bs[1];

    // histogram of low-9 dst bits
    h[t] = 0;
    __syncthreads();
    for (int i = t; i < c; i += 512)
        atomicAdd(&h[(slab[base + i].x >> 16) & (BKT_SZ - 1)], 1);
    __syncthreads();

    // exclusive scan of 512 bins via wave scans
    int v = h[t];
    int incl = wave_incl_scan(v);
    if (lane == 63) wtot[w] = incl;
    __syncthreads();
    int add = 0;
#pragma unroll
    for (int i = 0; i < 8; ++i) add += (i < w) ? wtot[i] : 0;
    int excl = add + incl - v;

    int g = (b << BKT_LOG) + t;
    if (g < N_NODES) start[g] = base + excl;
    if (b == NBKT - 1 && t == 0) start[N_NODES] = N_EDGES;

    h[t] = base + excl;                   // reuse as cursor
    __syncthreads();
    for (int i = t; i < c; i += 512) {
        uint2 r = slab[base + i];
        int p = atomicAdd(&h[(r.x >> 16) & (BKT_SZ - 1)], 1);
        edges[p] = (r.x & 0xFFFFu) | ((unsigned)f2bf(__uint_as_float(r.y)) << 16);
    }
}

// ---------- agg core (device): returns acc for node n's (es,f4) slice ----------
__device__ inline float4 agg_core(const unsigned short* __restrict__ hwb,
                                  const unsigned* __restrict__ edges,
                                  int i0, int i1, int es, int f4) {
    float4 acc = make_float4(0.f, 0.f, 0.f, 0.f);
    for (int base = i0; base < i1; base += 16) {
        int ia = base + es;
        int ib = base + 4 + es;
        int ic = base + 8 + es;
        int id = base + 12 + es;
        float wa = 0.f, wb = 0.f, wc = 0.f, wd = 0.f;
        float4 va = make_float4(0.f, 0.f, 0.f, 0.f);
        float4 vb = va, vc = va, vd = va;
        if (ia < i1) {
            unsigned e = edges[ia];
            wa = __uint_as_float(e & 0xFFFF0000u);
            ushort4 v = *(const ushort4*)&hwb[(long)(e & 0xFFFFu) * N_HID + f4];
            va = make_float4(bf2f(v.x), bf2f(v.y), bf2f(v.z), bf2f(v.w));
        }
        if (ib < i1) {
            unsigned e = edges[ib];
            wb = __uint_as_float(e & 0xFFFF0000u);
            ushort4 v = *(const ushort4*)&hwb[(long)(e & 0xFFFFu) * N_HID + f4];
            vb = make_float4(bf2f(v.x), bf2f(v.y), bf2f(v.z), bf2f(v.w));
        }
        if (ic < i1) {
            unsigned e = edges[ic];
            wc = __uint_as_float(e & 0xFFFF0000u);
            ushort4 v = *(const ushort4*)&hwb[(long)(e & 0xFFFFu) * N_HID + f4];
            vc = make_float4(bf2f(v.x), bf2f(v.y), bf2f(v.z), bf2f(v.w));
        }
        if (id < i1) {
            unsigned e = edges[id];
            wd = __uint_as_float(e & 0xFFFF0000u);
            ushort4 v = *(const ushort4*)&hwb[(long)(e & 0xFFFFu) * N_HID + f4];
            vd = make_float4(bf2f(v.x), bf2f(v.y), bf2f(v.z), bf2f(v.w));
        }
        fma4(acc, wa, va);
        fma4(acc, wb, vb);
        fma4(acc, wc, vc);
        fma4(acc, wd, vd);
    }
    acc.x += __shfl_xor(acc.x, 16); acc.y += __shfl_xor(acc.y, 16);
    acc.z += __shfl_xor(acc.z, 16); acc.w += __shfl_xor(acc.w, 16);
    acc.x += __shfl_xor(acc.x, 32); acc.y += __shfl_xor(acc.y, 32);
    acc.z += __shfl_xor(acc.z, 32); acc.w += __shfl_xor(acc.w, 32);
    return acc;
}

// ---------- K4: agg1 + bias + relu + gemm2 fused -> bf16 table hwb2 ----------
__global__ __launch_bounds__(256) void agg_gemm(const unsigned short* __restrict__ hwb,
                                                const unsigned* __restrict__ edges,
                                                const int* __restrict__ start,
                                                const float* __restrict__ b1,
                                                const float* __restrict__ w2,
                                                unsigned short* __restrict__ hwb2) {
    __shared__ float lw2[N_HID * N_HID];       // 16 KB
    __shared__ float hrow[4][N_HID];           // 1 KB
    int tid = threadIdx.x;
    for (int idx = tid * 4; idx < N_HID * N_HID; idx += 256 * 4)
        *(float4*)&lw2[idx] = *(const float4*)&w2[idx];
    __syncthreads();

    int n = (blockIdx.x * blockDim.x + tid) >> 6;
    if (n >= N_NODES) return;
    int wv = tid >> 6;
    int lane = tid & 63;
    int es = lane >> 4;
    int f4 = (lane & 15) * 4;

    float4 acc = agg_core(hwb, edges, start[n], start[n + 1], es, f4);

    if (es == 0) {
        float4 bias = *(const float4*)&b1[f4];
        acc.x = fmaxf(acc.x + bias.x, 0.f);
        acc.y = fmaxf(acc.y + bias.y, 0.f);
        acc.z = fmaxf(acc.z + bias.z, 0.f);
        acc.w = fmaxf(acc.w + bias.w, 0.f);
        *(float4*)&hrow[wv][f4] = acc;         // intra-wave LDS handoff
    }
    // same wave reads: DS ops in-order per wave; compiler inserts lgkmcnt
    float o2 = 0.f;
#pragma unroll 8
    for (int k = 0; k < N_HID; ++k)
        o2 = fmaf(hrow[wv][k], lw2[k * N_HID + lane], o2);
    hwb2[(long)n * N_HID + lane] = f2bf(o2);
}

// ---------- K5: agg2 + b2 -> out (f32) ----------
__global__ __launch_bounds__(256) void agg_out(const unsigned short* __restrict__ hwb2,
                                               const unsigned* __restrict__ edges,
                                               const int* __restrict__ start,
                                               const float* __restrict__ b2,
                                               float* __restrict__ o) {
    int tid = threadIdx.x;
    int n = (blockIdx.x * blockDim.x + tid) >> 6;
    if (n >= N_NODES) return;
    int lane = tid & 63;
    int es = lane >> 4;
    int f4 = (lane & 15) * 4;

    float4 acc = agg_core(hwb2, edges, start[n], start[n + 1], es, f4);

    if (es == 0) {
        float4 bias = *(const float4*)&b2[f4];
        acc.x += bias.x; acc.y += bias.y; acc.z += bias.z; acc.w += bias.w;
        *(float4*)&o[(long)n * N_HID + f4] = acc;
    }
}

extern "C" void kernel_launch(void* const* d_in, const int* in_sizes, int n_in,
                              void* d_out, int out_size, void* d_ws, size_t ws_size,
                              hipStream_t stream) {
    const float* x  = (const float*)d_in[0];
    const int*   ei = (const int*)d_in[1];   // [2, E] flat: src then dst
    const float* ew = (const float*)d_in[2];
    const float* w1 = (const float*)d_in[3];
    const float* b1 = (const float*)d_in[4];
    const float* w2 = (const float*)d_in[5];
    const float* b2 = (const float*)d_in[6];
    float* out = (float*)d_out;

    const int* src = ei;
    const int* dst = ei + N_EDGES;

    char* ws = (char*)d_ws;
    unsigned short* hwb  = (unsigned short*)ws;                      // 6.4 MB
    unsigned short* hwb2 = (unsigned short*)(ws + (size_t)7  * 1024 * 1024); // 6.4 MB
    uint2*    slab  = (uint2*)   (ws + (size_t)14 * 1024 * 1024);    // 6.4 MB
    unsigned* edges = (unsigned*)(ws + (size_t)21 * 1024 * 1024);    // 3.2 MB
    int*      start = (int*)     (ws + (size_t)25 * 1024 * 1024);    // 50001 ints
    int*      cnt   = start + N_NODES + 8;                           // NB1*NBKT
    int*      cnt_t = cnt + NB1 * NBKT;                              // NBKT*NB1

    dim3 blk(256);
    dim3 ngrid((N_NODES * N_HID + 255) / 256);   // 12500 (4 nodes/block)

    // K1: hist blocks first (start immediately), then gemm1 blocks
    gemm1_hist<<<dim3(NB1 + GG), blk, 0, stream>>>(x, w1, hwb, dst, cnt, cnt_t);
    // K2: bucket partition (self-computed offsets)
    binscatter<<<dim3(NB1), blk, 0, stream>>>(src, dst, ew, cnt, cnt_t, slab);
    // K3: per-bucket dst sort -> packed edges + start[]
    sort_bucket<<<dim3(NBKT), dim3(512), 0, stream>>>(slab, cnt_t, edges, start);
    // K4: agg1 + b1 + relu + gemm2 -> bf16 table
    agg_gemm<<<ngrid, blk, 0, stream>>>(hwb, edges, start, b1, w2, hwb2);
    // K5: agg2 + b2 -> out
    agg_out<<<ngrid, blk, 0, stream>>>(hwb2, edges, start, b2, out);
}

// Round 11
// 134.744 us; speedup vs baseline: 4.1368x; 1.0279x over previous
//
#include <hip/hip_runtime.h>

#define N_NODES 50000
#define N_EDGES 800000
#define N_FEAT  128
#define N_HID   64

#define BKT_LOG 9
#define BKT_SZ  512                                  // nodes per bucket
#define NBKT    ((N_NODES + BKT_SZ - 1) / BKT_SZ)    // 98
#define CH      4096                                 // edges per partition block
#define NB1     ((N_EDGES + CH - 1) / CH)            // 196
#define GG      ((N_NODES + 31) / 32)                // 1563 gemm blocks

__device__ inline void fma4(float4& acc, float s, const float4& w) {
    acc.x = fmaf(s, w.x, acc.x);
    acc.y = fmaf(s, w.y, acc.y);
    acc.z = fmaf(s, w.z, acc.z);
    acc.w = fmaf(s, w.w, acc.w);
}

__device__ inline unsigned short f2bf(float f) {          // RNE f32 -> bf16
    unsigned u = __float_as_uint(f);
    u = u + 0x7FFFu + ((u >> 16) & 1u);
    return (unsigned short)(u >> 16);
}
__device__ inline float bf2f(unsigned short v) { return __uint_as_float(((unsigned)v) << 16); }

__device__ inline int wave_incl_scan(int v) {
    int lane = threadIdx.x & 63;
#pragma unroll
    for (int o = 1; o < 64; o <<= 1) {
        int u = __shfl_up(v, o);
        if (lane >= o) v += u;
    }
    return v;
}

// ---------- K1: gemm1 (x@w1 -> bf16 hwb) fused with binhist ----------
__global__ __launch_bounds__(256) void gemm1_hist(const float* __restrict__ a,
                                                  const float* __restrict__ w,
                                                  unsigned short* __restrict__ o,
                                                  const int* __restrict__ dst,
                                                  int* __restrict__ cnt,
                                                  int* __restrict__ cnt_t) {
    int tid = threadIdx.x;
    if (blockIdx.x < NB1) {                      // ---- histogram part ----
        __shared__ int h[NBKT];
        int bid = blockIdx.x;
        if (tid < NBKT) h[tid] = 0;
        __syncthreads();
        int e0 = bid * CH;
        for (int i = tid; i < CH; i += 256) {
            int e = e0 + i;
            if (e < N_EDGES) atomicAdd(&h[dst[e] >> BKT_LOG], 1);
        }
        __syncthreads();
        if (tid < NBKT) {
            int v = h[tid];
            cnt[bid * NBKT + tid] = v;
            cnt_t[tid * NB1 + bid] = v;
        }
        return;
    }
    // ---- gemm part ----
    __shared__ float lw[N_FEAT * N_HID];
    for (int idx = tid * 4; idx < N_FEAT * N_HID; idx += 256 * 4)
        *(float4*)&lw[idx] = *(const float4*)&w[idx];
    __syncthreads();

    int blk = blockIdx.x - NB1;
    int row0 = blk * 32 + (tid >> 4) * 2;
    if (row0 >= N_NODES) return;
    bool two = (row0 + 1) < N_NODES;
    int c4 = (tid & 15) * 4;

    const float* a0 = a + (long)row0 * N_FEAT;
    const float* a1 = two ? (a0 + N_FEAT) : a0;

    float4 acc0 = make_float4(0.f, 0.f, 0.f, 0.f);
    float4 acc1 = acc0;

#pragma unroll 8
    for (int k4 = 0; k4 < N_FEAT / 4; ++k4) {
        float4 xa = *(const float4*)(a0 + k4 * 4);
        float4 xb = *(const float4*)(a1 + k4 * 4);
        const float* wk = &lw[(k4 * 4) * N_HID + c4];
        float4 w0 = *(const float4*)(wk);
        float4 w1 = *(const float4*)(wk + N_HID);
        float4 w2 = *(const float4*)(wk + 2 * N_HID);
        float4 w3 = *(const float4*)(wk + 3 * N_HID);
        fma4(acc0, xa.x, w0); fma4(acc1, xb.x, w0);
        fma4(acc0, xa.y, w1); fma4(acc1, xb.y, w1);
        fma4(acc0, xa.z, w2); fma4(acc1, xb.z, w2);
        fma4(acc0, xa.w, w3); fma4(acc1, xb.w, w3);
    }

    unsigned short* op = o + (long)row0 * N_HID + c4;
    *(ushort4*)op = make_ushort4(f2bf(acc0.x), f2bf(acc0.y), f2bf(acc0.z), f2bf(acc0.w));
    if (two)
        *(ushort4*)(op + N_HID) = make_ushort4(f2bf(acc1.x), f2bf(acc1.y), f2bf(acc1.z), f2bf(acc1.w));
}

// ---------- plain tiled GEMM (f32 in, bf16 out), for layer 2 ----------
template <int K>
__global__ __launch_bounds__(256) void gemm_tile(const float* __restrict__ a,
                                                 const float* __restrict__ w,
                                                 unsigned short* __restrict__ o) {
    __shared__ float lw[K * N_HID];
    int tid = threadIdx.x;
    for (int idx = tid * 4; idx < K * N_HID; idx += 256 * 4)
        *(float4*)&lw[idx] = *(const float4*)&w[idx];
    __syncthreads();

    int row0 = blockIdx.x * 32 + (tid >> 4) * 2;
    if (row0 >= N_NODES) return;
    bool two = (row0 + 1) < N_NODES;
    int c4 = (tid & 15) * 4;

    const float* a0 = a + (long)row0 * K;
    const float* a1 = two ? (a0 + K) : a0;

    float4 acc0 = make_float4(0.f, 0.f, 0.f, 0.f);
    float4 acc1 = acc0;

#pragma unroll 8
    for (int k4 = 0; k4 < K / 4; ++k4) {
        float4 xa = *(const float4*)(a0 + k4 * 4);
        float4 xb = *(const float4*)(a1 + k4 * 4);
        const float* wk = &lw[(k4 * 4) * N_HID + c4];
        float4 w0 = *(const float4*)(wk);
        float4 w1 = *(const float4*)(wk + N_HID);
        float4 w2 = *(const float4*)(wk + 2 * N_HID);
        float4 w3 = *(const float4*)(wk + 3 * N_HID);
        fma4(acc0, xa.x, w0); fma4(acc1, xb.x, w0);
        fma4(acc0, xa.y, w1); fma4(acc1, xb.y, w1);
        fma4(acc0, xa.z, w2); fma4(acc1, xb.z, w2);
        fma4(acc0, xa.w, w3); fma4(acc1, xb.w, w3);
    }

    unsigned short* op = o + (long)row0 * N_HID + c4;
    *(ushort4*)op = make_ushort4(f2bf(acc0.x), f2bf(acc0.y), f2bf(acc0.z), f2bf(acc0.w));
    if (two)
        *(ushort4*)(op + N_HID) = make_ushort4(f2bf(acc1.x), f2bf(acc1.y), f2bf(acc1.z), f2bf(acc1.w));
}

// ---------- K2: binscatter, self-computing cursor bases ----------
__global__ __launch_bounds__(256) void binscatter(const int* __restrict__ src,
                                                  const int* __restrict__ dst,
                                                  const float* __restrict__ ew,
                                                  const int* __restrict__ cnt,
                                                  const int* __restrict__ cnt_t,
                                                  uint2* __restrict__ slab) {
    __shared__ int cur[NBKT];
    __shared__ int wtot[2];
    int t = threadIdx.x;
    int b = blockIdx.x;

    int tot = 0, pre = 0;
    if (t < NBKT) {
        const int4* p = (const int4*)(cnt_t + t * NB1);   // NB1 % 4 == 0
        for (int q = 0; q < NB1 / 4; ++q) {
            int4 v = p[q];
            tot += v.x + v.y + v.z + v.w;
        }
        int p0 = 0, p1 = 0, p2 = 0, p3 = 0;
        int j = 0;
        for (; j + 4 <= b; j += 4) {
            p0 += cnt[(j + 0) * NBKT + t];
            p1 += cnt[(j + 1) * NBKT + t];
            p2 += cnt[(j + 2) * NBKT + t];
            p3 += cnt[(j + 3) * NBKT + t];
        }
        for (; j < b; ++j) p0 += cnt[j * NBKT + t];
        pre = p0 + p1 + p2 + p3;
    }
    int incl = wave_incl_scan(tot);                   // waves 0,1 cover t<98
    if (t < 128 && (t & 63) == 63) wtot[t >> 6] = incl;
    __syncthreads();
    if (t < NBKT) {
        int bstart_t = (t >= 64 ? wtot[0] : 0) + incl - tot;  // exclusive prefix
        cur[t] = bstart_t + pre;
    }
    __syncthreads();

    int e0 = b * CH;
    for (int i = t; i < CH; i += 256) {
        int e = e0 + i;
        if (e >= N_EDGES) continue;
        int d = dst[e];
        int bin = d >> BKT_LOG;
        int p = atomicAdd(&cur[bin], 1);
        slab[p] = make_uint2((unsigned)src[e] | ((unsigned)(d & (BKT_SZ - 1)) << 16),
                             __float_as_uint(ew[e]));
    }
}

// ---------- K3: per-bucket counting sort (self-computed bstart, wave scans) ----------
__global__ __launch_bounds__(512) void sort_bucket(const uint2* __restrict__ slab,
                                                   const int* __restrict__ cnt_t,
                                                   unsigned* __restrict__ edges,
                                                   int* __restrict__ start) {
    __shared__ int tt[NBKT];
    __shared__ int h[BKT_SZ];
    __shared__ int wtot[8];
    __shared__ int bs[2];
    int b = blockIdx.x;
    int t = threadIdx.x;
    int lane = t & 63;
    int w = t >> 6;

    if (t < NBKT) {
        int s = 0;
        const int4* p = (const int4*)(cnt_t + t * NB1);
        for (int q = 0; q < NB1 / 4; ++q) {
            int4 v = p[q];
            s += v.x + v.y + v.z + v.w;
        }
        tt[t] = s;
    }
    __syncthreads();
    if (t < 64) {
        int v = (t < b ? tt[t] : 0) + (t + 64 < b ? tt[t + 64] : 0);
#pragma unroll
        for (int o = 32; o >= 1; o >>= 1) v += __shfl_xor(v, o);
        if (t == 0) { bs[0] = v; bs[1] = tt[b]; }
    }
    __syncthreads();
    int base = bs[0];
    int c = bs[1];

    h[t] = 0;
    __syncthreads();
    for (int i = t; i < c; i += 512)
        atomicAdd(&h[(slab[base + i].x >> 16) & (BKT_SZ - 1)], 1);
    __syncthreads();

    int v = h[t];
    int incl = wave_incl_scan(v);
    if (lane == 63) wtot[w] = incl;
    __syncthreads();
    int add = 0;
#pragma unroll
    for (int i = 0; i < 8; ++i) add += (i < w) ? wtot[i] : 0;
    int excl = add + incl - v;

    int g = (b << BKT_LOG) + t;
    if (g < N_NODES) start[g] = base + excl;
    if (b == NBKT - 1 && t == 0) start[N_NODES] = N_EDGES;

    h[t] = base + excl;                   // reuse as cursor
    __syncthreads();
    for (int i = t; i < c; i += 512) {
        uint2 r = slab[base + i];
        int p = atomicAdd(&h[(r.x >> 16) & (BKT_SZ - 1)], 1);
        edges[p] = (r.x & 0xFFFFu) | ((unsigned)f2bf(__uint_as_float(r.y)) << 16);
    }
}

// ---------- agg core ----------
__device__ inline float4 agg_core(const unsigned short* __restrict__ hwb,
                                  const unsigned* __restrict__ edges,
                                  int i0, int i1, int es, int f4) {
    float4 acc = make_float4(0.f, 0.f, 0.f, 0.f);
    for (int base = i0; base < i1; base += 16) {
        int ia = base + es;
        int ib = base + 4 + es;
        int ic = base + 8 + es;
        int id = base + 12 + es;
        float wa = 0.f, wb = 0.f, wc = 0.f, wd = 0.f;
        float4 va = make_float4(0.f, 0.f, 0.f, 0.f);
        float4 vb = va, vc = va, vd = va;
        if (ia < i1) {
            unsigned e = edges[ia];
            wa = __uint_as_float(e & 0xFFFF0000u);
            ushort4 v = *(const ushort4*)&hwb[(long)(e & 0xFFFFu) * N_HID + f4];
            va = make_float4(bf2f(v.x), bf2f(v.y), bf2f(v.z), bf2f(v.w));
        }
        if (ib < i1) {
            unsigned e = edges[ib];
            wb = __uint_as_float(e & 0xFFFF0000u);
            ushort4 v = *(const ushort4*)&hwb[(long)(e & 0xFFFFu) * N_HID + f4];
            vb = make_float4(bf2f(v.x), bf2f(v.y), bf2f(v.z), bf2f(v.w));
        }
        if (ic < i1) {
            unsigned e = edges[ic];
            wc = __uint_as_float(e & 0xFFFF0000u);
            ushort4 v = *(const ushort4*)&hwb[(long)(e & 0xFFFFu) * N_HID + f4];
            vc = make_float4(bf2f(v.x), bf2f(v.y), bf2f(v.z), bf2f(v.w));
        }
        if (id < i1) {
            unsigned e = edges[id];
            wd = __uint_as_float(e & 0xFFFF0000u);
            ushort4 v = *(const ushort4*)&hwb[(long)(e & 0xFFFFu) * N_HID + f4];
            vd = make_float4(bf2f(v.x), bf2f(v.y), bf2f(v.z), bf2f(v.w));
        }
        fma4(acc, wa, va);
        fma4(acc, wb, vb);
        fma4(acc, wc, vc);
        fma4(acc, wd, vd);
    }
    acc.x += __shfl_xor(acc.x, 16); acc.y += __shfl_xor(acc.y, 16);
    acc.z += __shfl_xor(acc.z, 16); acc.w += __shfl_xor(acc.w, 16);
    acc.x += __shfl_xor(acc.x, 32); acc.y += __shfl_xor(acc.y, 32);
    acc.z += __shfl_xor(acc.z, 32); acc.w += __shfl_xor(acc.w, 32);
    return acc;
}

// ---------- K4: agg1 + b1 + relu -> h (f32) ----------
__global__ __launch_bounds__(256) void agg_relu(const unsigned short* __restrict__ hwb,
                                                const unsigned* __restrict__ edges,
                                                const int* __restrict__ start,
                                                const float* __restrict__ b1,
                                                float* __restrict__ h) {
    int tid = threadIdx.x;
    int n = (blockIdx.x * blockDim.x + tid) >> 6;
    if (n >= N_NODES) return;
    int lane = tid & 63;
    int es = lane >> 4;
    int f4 = (lane & 15) * 4;

    float4 acc = agg_core(hwb, edges, start[n], start[n + 1], es, f4);

    if (es == 0) {
        float4 bias = *(const float4*)&b1[f4];
        acc.x = fmaxf(acc.x + bias.x, 0.f);
        acc.y = fmaxf(acc.y + bias.y, 0.f);
        acc.z = fmaxf(acc.z + bias.z, 0.f);
        acc.w = fmaxf(acc.w + bias.w, 0.f);
        *(float4*)&h[(long)n * N_HID + f4] = acc;
    }
}

// ---------- K6: agg2 + b2 -> out (f32) ----------
__global__ __launch_bounds__(256) void agg_out(const unsigned short* __restrict__ hwb2,
                                               const unsigned* __restrict__ edges,
                                               const int* __restrict__ start,
                                               const float* __restrict__ b2,
                                               float* __restrict__ o) {
    int tid = threadIdx.x;
    int n = (blockIdx.x * blockDim.x + tid) >> 6;
    if (n >= N_NODES) return;
    int lane = tid & 63;
    int es = lane >> 4;
    int f4 = (lane & 15) * 4;

    float4 acc = agg_core(hwb2, edges, start[n], start[n + 1], es, f4);

    if (es == 0) {
        float4 bias = *(const float4*)&b2[f4];
        acc.x += bias.x; acc.y += bias.y; acc.z += bias.z; acc.w += bias.w;
        *(float4*)&o[(long)n * N_HID + f4] = acc;
    }
}

extern "C" void kernel_launch(void* const* d_in, const int* in_sizes, int n_in,
                              void* d_out, int out_size, void* d_ws, size_t ws_size,
                              hipStream_t stream) {
    const float* x  = (const float*)d_in[0];
    const int*   ei = (const int*)d_in[1];   // [2, E] flat: src then dst
    const float* ew = (const float*)d_in[2];
    const float* w1 = (const float*)d_in[3];
    const float* b1 = (const float*)d_in[4];
    const float* w2 = (const float*)d_in[5];
    const float* b2 = (const float*)d_in[6];
    float* out = (float*)d_out;

    const int* src = ei;
    const int* dst = ei + N_EDGES;

    char* ws = (char*)d_ws;
    unsigned short* hwb  = (unsigned short*)ws;                      // 6.4 MB
    unsigned short* hwb2 = (unsigned short*)(ws + (size_t)7  * 1024 * 1024); // 6.4 MB
    uint2*    slab  = (uint2*)   (ws + (size_t)14 * 1024 * 1024);    // 6.4 MB
    unsigned* edges = (unsigned*)(ws + (size_t)21 * 1024 * 1024);    // 3.2 MB
    int*      start = (int*)     (ws + (size_t)25 * 1024 * 1024);    // 50001 ints
    int*      cnt   = start + N_NODES + 8;                           // NB1*NBKT
    int*      cnt_t = cnt + NB1 * NBKT;                              // NBKT*NB1

    dim3 blk(256);
    dim3 ngrid((N_NODES * N_HID + 255) / 256);   // 12500 (4 nodes/block)

    // K1: hist blocks first, then gemm1 blocks (one launch, parallel)
    gemm1_hist<<<dim3(NB1 + GG), blk, 0, stream>>>(x, w1, hwb, dst, cnt, cnt_t);
    // K2: bucket partition (self-computed offsets)
    binscatter<<<dim3(NB1), blk, 0, stream>>>(src, dst, ew, cnt, cnt_t, slab);
    // K3: per-bucket dst sort -> packed edges + start[]
    sort_bucket<<<dim3(NBKT), dim3(512), 0, stream>>>(slab, cnt_t, edges, start);
    // K4: agg1 + b1 + relu -> h (f32, staged in d_out)
    agg_relu<<<ngrid, blk, 0, stream>>>(hwb, edges, start, b1, out);
    // K5: gemm2: h @ w2 -> bf16 hwb2 (tiled, efficient)
    gemm_tile<N_HID><<<dim3(GG), blk, 0, stream>>>(out, w2, hwb2);
    // K6: agg2 + b2 -> out
    agg_out<<<ngrid, blk, 0, stream>>>(hwb2, edges, start, b2, out);
}

// Round 12
// 127.834 us; speedup vs baseline: 4.3604x; 1.0541x over previous
//
#include <hip/hip_runtime.h>

#define N_NODES 50000
#define N_EDGES 800000
#define N_FEAT  128
#define N_HID   64

#define BKT_LOG 9
#define BKT_SZ  512                                  // nodes per bucket
#define NBKT    ((N_NODES + BKT_SZ - 1) / BKT_SZ)    // 98
#define CH      4096                                 // edges per partition block
#define NB1     ((N_EDGES + CH - 1) / CH)            // 196
#define GROWS   64                                   // rows per gemm block
#define GG      ((N_NODES + GROWS - 1) / GROWS)      // 782 gemm blocks
#define AGG_B   2048                                 // agg grid (grid-stride)

__device__ inline void fma4(float4& acc, float s, const float4& w) {
    acc.x = fmaf(s, w.x, acc.x);
    acc.y = fmaf(s, w.y, acc.y);
    acc.z = fmaf(s, w.z, acc.z);
    acc.w = fmaf(s, w.w, acc.w);
}

__device__ inline unsigned short f2bf(float f) {          // RNE f32 -> bf16
    unsigned u = __float_as_uint(f);
    u = u + 0x7FFFu + ((u >> 16) & 1u);
    return (unsigned short)(u >> 16);
}
__device__ inline float bf2f(unsigned short v) { return __uint_as_float(((unsigned)v) << 16); }

__device__ inline int wave_incl_scan(int v) {
    int lane = threadIdx.x & 63;
#pragma unroll
    for (int o = 1; o < 64; o <<= 1) {
        int u = __shfl_up(v, o);
        if (lane >= o) v += u;
    }
    return v;
}

// ---------- gemm core: 2 rows x 8 cols per thread, 64 rows/block ----------
template <int K>
__device__ inline void gemm_body(const float* __restrict__ a, const float* __restrict__ lw,
                                 unsigned short* __restrict__ o, int blk) {
    int tid = threadIdx.x;
    int rp = tid >> 3;                 // 0..31
    int c0 = (tid & 7) * 8;            // 0,8,...,56
    int row0 = blk * GROWS + rp * 2;
    if (row0 >= N_NODES) return;
    bool two = (row0 + 1) < N_NODES;

    const float* a0 = a + (long)row0 * K;
    const float* a1 = two ? (a0 + K) : a0;

    float4 aA0 = make_float4(0.f, 0.f, 0.f, 0.f), aA1 = aA0;  // row0 cols c0..c0+3, c0+4..c0+7
    float4 aB0 = aA0, aB1 = aA0;                              // row1

#pragma unroll 4
    for (int k4 = 0; k4 < K / 4; ++k4) {
        float4 xa = *(const float4*)(a0 + k4 * 4);
        float4 xb = *(const float4*)(a1 + k4 * 4);
#pragma unroll
        for (int j = 0; j < 4; ++j) {
            const float* wk = &lw[(k4 * 4 + j) * N_HID + c0];
            float4 w0 = *(const float4*)(wk);
            float4 w1 = *(const float4*)(wk + 4);
            float sa = (j == 0) ? xa.x : (j == 1) ? xa.y : (j == 2) ? xa.z : xa.w;
            float sb = (j == 0) ? xb.x : (j == 1) ? xb.y : (j == 2) ? xb.z : xb.w;
            fma4(aA0, sa, w0); fma4(aA1, sa, w1);
            fma4(aB0, sb, w0); fma4(aB1, sb, w1);
        }
    }

    unsigned short* op = o + (long)row0 * N_HID + c0;
    *(ushort4*)op = make_ushort4(f2bf(aA0.x), f2bf(aA0.y), f2bf(aA0.z), f2bf(aA0.w));
    *(ushort4*)(op + 4) = make_ushort4(f2bf(aA1.x), f2bf(aA1.y), f2bf(aA1.z), f2bf(aA1.w));
    if (two) {
        *(ushort4*)(op + N_HID) = make_ushort4(f2bf(aB0.x), f2bf(aB0.y), f2bf(aB0.z), f2bf(aB0.w));
        *(ushort4*)(op + N_HID + 4) = make_ushort4(f2bf(aB1.x), f2bf(aB1.y), f2bf(aB1.z), f2bf(aB1.w));
    }
}

// ---------- K1: gemm1 (x@w1 -> bf16 hwb) fused with binhist ----------
__global__ __launch_bounds__(256) void gemm1_hist(const float* __restrict__ a,
                                                  const float* __restrict__ w,
                                                  unsigned short* __restrict__ o,
                                                  const int* __restrict__ dst,
                                                  int* __restrict__ cnt,
                                                  int* __restrict__ cnt_t) {
    __shared__ float lw[N_FEAT * N_HID];        // 32 KB (also covers hist's needs)
    int tid = threadIdx.x;
    if (blockIdx.x < NB1) {                      // ---- histogram part ----
        int* h = (int*)lw;                       // reuse LDS
        int bid = blockIdx.x;
        if (tid < NBKT) h[tid] = 0;
        __syncthreads();
        int e0 = bid * CH;
        for (int i = tid; i < CH; i += 256) {
            int e = e0 + i;
            if (e < N_EDGES) atomicAdd(&h[dst[e] >> BKT_LOG], 1);
        }
        __syncthreads();
        if (tid < NBKT) {
            int v = h[tid];
            cnt[bid * NBKT + tid] = v;
            cnt_t[tid * NB1 + bid] = v;
        }
        return;
    }
    // ---- gemm part ----
    for (int idx = tid * 4; idx < N_FEAT * N_HID; idx += 256 * 4)
        *(float4*)&lw[idx] = *(const float4*)&w[idx];
    __syncthreads();
    gemm_body<N_FEAT>(a, lw, o, blockIdx.x - NB1);
}

// ---------- plain tiled GEMM (f32 in, bf16 out), for layer 2 ----------
template <int K>
__global__ __launch_bounds__(256) void gemm_tile(const float* __restrict__ a,
                                                 const float* __restrict__ w,
                                                 unsigned short* __restrict__ o) {
    __shared__ float lw[K * N_HID];
    int tid = threadIdx.x;
    for (int idx = tid * 4; idx < K * N_HID; idx += 256 * 4)
        *(float4*)&lw[idx] = *(const float4*)&w[idx];
    __syncthreads();
    gemm_body<K>(a, lw, o, blockIdx.x);
}

// ---------- K2: binscatter, self-computing cursor bases ----------
__global__ __launch_bounds__(256) void binscatter(const int* __restrict__ src,
                                                  const int* __restrict__ dst,
                                                  const float* __restrict__ ew,
                                                  const int* __restrict__ cnt,
                                                  const int* __restrict__ cnt_t,
                                                  uint2* __restrict__ slab) {
    __shared__ int cur[NBKT];
    __shared__ int wtot[2];
    int t = threadIdx.x;
    int b = blockIdx.x;

    int tot = 0, pre = 0;
    if (t < NBKT) {
        const int4* p = (const int4*)(cnt_t + t * NB1);   // NB1 % 4 == 0
        for (int q = 0; q < NB1 / 4; ++q) {
            int4 v = p[q];
            tot += v.x + v.y + v.z + v.w;
        }
        int p0 = 0, p1 = 0, p2 = 0, p3 = 0;
        int j = 0;
        for (; j + 4 <= b; j += 4) {
            p0 += cnt[(j + 0) * NBKT + t];
            p1 += cnt[(j + 1) * NBKT + t];
            p2 += cnt[(j + 2) * NBKT + t];
            p3 += cnt[(j + 3) * NBKT + t];
        }
        for (; j < b; ++j) p0 += cnt[j * NBKT + t];
        pre = p0 + p1 + p2 + p3;
    }
    int incl = wave_incl_scan(tot);                   // waves 0,1 cover t<98
    if (t < 128 && (t & 63) == 63) wtot[t >> 6] = incl;
    __syncthreads();
    if (t < NBKT) {
        int bstart_t = (t >= 64 ? wtot[0] : 0) + incl - tot;  // exclusive prefix
        cur[t] = bstart_t + pre;
    }
    __syncthreads();

    int e0 = b * CH;
    for (int i = t; i < CH; i += 256) {
        int e = e0 + i;
        if (e >= N_EDGES) continue;
        int d = dst[e];
        int bin = d >> BKT_LOG;
        int p = atomicAdd(&cur[bin], 1);
        slab[p] = make_uint2((unsigned)src[e] | ((unsigned)(d & (BKT_SZ - 1)) << 16),
                             __float_as_uint(ew[e]));
    }
}

// ---------- K3: per-bucket counting sort (self-computed bstart, wave scans) ----------
__global__ __launch_bounds__(512) void sort_bucket(const uint2* __restrict__ slab,
                                                   const int* __restrict__ cnt_t,
                                                   unsigned* __restrict__ edges,
                                                   int* __restrict__ start) {
    __shared__ int tt[NBKT];
    __shared__ int h[BKT_SZ];
    __shared__ int wtot[8];
    __shared__ int bs[2];
    int b = blockIdx.x;
    int t = threadIdx.x;
    int lane = t & 63;
    int w = t >> 6;

    if (t < NBKT) {
        int s = 0;
        const int4* p = (const int4*)(cnt_t + t * NB1);
        for (int q = 0; q < NB1 / 4; ++q) {
            int4 v = p[q];
            s += v.x + v.y + v.z + v.w;
        }
        tt[t] = s;
    }
    __syncthreads();
    if (t < 64) {
        int v = (t < b ? tt[t] : 0) + (t + 64 < b ? tt[t + 64] : 0);
#pragma unroll
        for (int o = 32; o >= 1; o >>= 1) v += __shfl_xor(v, o);
        if (t == 0) { bs[0] = v; bs[1] = tt[b]; }
    }
    __syncthreads();
    int base = bs[0];
    int c = bs[1];

    h[t] = 0;
    __syncthreads();
    for (int i = t; i < c; i += 512)
        atomicAdd(&h[(slab[base + i].x >> 16) & (BKT_SZ - 1)], 1);
    __syncthreads();

    int v = h[t];
    int incl = wave_incl_scan(v);
    if (lane == 63) wtot[w] = incl;
    __syncthreads();
    int add = 0;
#pragma unroll
    for (int i = 0; i < 8; ++i) add += (i < w) ? wtot[i] : 0;
    int excl = add + incl - v;

    int g = (b << BKT_LOG) + t;
    if (g < N_NODES) start[g] = base + excl;
    if (b == NBKT - 1 && t == 0) start[N_NODES] = N_EDGES;

    h[t] = base + excl;                   // reuse as cursor
    __syncthreads();
    for (int i = t; i < c; i += 512) {
        uint2 r = slab[base + i];
        int p = atomicAdd(&h[(r.x >> 16) & (BKT_SZ - 1)], 1);
        edges[p] = (r.x & 0xFFFFu) | ((unsigned)f2bf(__uint_as_float(r.y)) << 16);
    }
}

// ---------- agg core ----------
__device__ inline float4 agg_core(const unsigned short* __restrict__ hwb,
                                  const unsigned* __restrict__ edges,
                                  int i0, int i1, int es, int f4) {
    float4 acc = make_float4(0.f, 0.f, 0.f, 0.f);
    for (int base = i0; base < i1; base += 16) {
        int ia = base + es;
        int ib = base + 4 + es;
        int ic = base + 8 + es;
        int id = base + 12 + es;
        float wa = 0.f, wb = 0.f, wc = 0.f, wd = 0.f;
        float4 va = make_float4(0.f, 0.f, 0.f, 0.f);
        float4 vb = va, vc = va, vd = va;
        if (ia < i1) {
            unsigned e = edges[ia];
            wa = __uint_as_float(e & 0xFFFF0000u);
            ushort4 v = *(const ushort4*)&hwb[(long)(e & 0xFFFFu) * N_HID + f4];
            va = make_float4(bf2f(v.x), bf2f(v.y), bf2f(v.z), bf2f(v.w));
        }
        if (ib < i1) {
            unsigned e = edges[ib];
            wb = __uint_as_float(e & 0xFFFF0000u);
            ushort4 v = *(const ushort4*)&hwb[(long)(e & 0xFFFFu) * N_HID + f4];
            vb = make_float4(bf2f(v.x), bf2f(v.y), bf2f(v.z), bf2f(v.w));
        }
        if (ic < i1) {
            unsigned e = edges[ic];
            wc = __uint_as_float(e & 0xFFFF0000u);
            ushort4 v = *(const ushort4*)&hwb[(long)(e & 0xFFFFu) * N_HID + f4];
            vc = make_float4(bf2f(v.x), bf2f(v.y), bf2f(v.z), bf2f(v.w));
        }
        if (id < i1) {
            unsigned e = edges[id];
            wd = __uint_as_float(e & 0xFFFF0000u);
            ushort4 v = *(const ushort4*)&hwb[(long)(e & 0xFFFFu) * N_HID + f4];
            vd = make_float4(bf2f(v.x), bf2f(v.y), bf2f(v.z), bf2f(v.w));
        }
        fma4(acc, wa, va);
        fma4(acc, wb, vb);
        fma4(acc, wc, vc);
        fma4(acc, wd, vd);
    }
    acc.x += __shfl_xor(acc.x, 16); acc.y += __shfl_xor(acc.y, 16);
    acc.z += __shfl_xor(acc.z, 16); acc.w += __shfl_xor(acc.w, 16);
    acc.x += __shfl_xor(acc.x, 32); acc.y += __shfl_xor(acc.y, 32);
    acc.z += __shfl_xor(acc.z, 32); acc.w += __shfl_xor(acc.w, 32);
    return acc;
}

// ---------- K4: agg1 + b1 + relu -> h (f32), grid-stride ----------
__global__ __launch_bounds__(256) void agg_relu(const unsigned short* __restrict__ hwb,
                                                const unsigned* __restrict__ edges,
                                                const int* __restrict__ start,
                                                const float* __restrict__ b1,
                                                float* __restrict__ h) {
    int tid = threadIdx.x;
    int lane = tid & 63;
    int es = lane >> 4;
    int f4 = (lane & 15) * 4;
    float4 bias = *(const float4*)&b1[f4];
    for (int n = blockIdx.x * 4 + (tid >> 6); n < N_NODES; n += AGG_B * 4) {
        float4 acc = agg_core(hwb, edges, start[n], start[n + 1], es, f4);
        if (es == 0) {
            acc.x = fmaxf(acc.x + bias.x, 0.f);
            acc.y = fmaxf(acc.y + bias.y, 0.f);
            acc.z = fmaxf(acc.z + bias.z, 0.f);
            acc.w = fmaxf(acc.w + bias.w, 0.f);
            *(float4*)&h[(long)n * N_HID + f4] = acc;
        }
    }
}

// ---------- K6: agg2 + b2 -> out (f32), grid-stride ----------
__global__ __launch_bounds__(256) void agg_out(const unsigned short* __restrict__ hwb2,
                                               const unsigned* __restrict__ edges,
                                               const int* __restrict__ start,
                                               const float* __restrict__ b2,
                                               float* __restrict__ o) {
    int tid = threadIdx.x;
    int lane = tid & 63;
    int es = lane >> 4;
    int f4 = (lane & 15) * 4;
    float4 bias = *(const float4*)&b2[f4];
    for (int n = blockIdx.x * 4 + (tid >> 6); n < N_NODES; n += AGG_B * 4) {
        float4 acc = agg_core(hwb2, edges, start[n], start[n + 1], es, f4);
        if (es == 0) {
            acc.x += bias.x; acc.y += bias.y; acc.z += bias.z; acc.w += bias.w;
            *(float4*)&o[(long)n * N_HID + f4] = acc;
        }
    }
}

extern "C" void kernel_launch(void* const* d_in, const int* in_sizes, int n_in,
                              void* d_out, int out_size, void* d_ws, size_t ws_size,
                              hipStream_t stream) {
    const float* x  = (const float*)d_in[0];
    const int*   ei = (const int*)d_in[1];   // [2, E] flat: src then dst
    const float* ew = (const float*)d_in[2];
    const float* w1 = (const float*)d_in[3];
    const float* b1 = (const float*)d_in[4];
    const float* w2 = (const float*)d_in[5];
    const float* b2 = (const float*)d_in[6];
    float* out = (float*)d_out;

    const int* src = ei;
    const int* dst = ei + N_EDGES;

    char* ws = (char*)d_ws;
    unsigned short* hwb  = (unsigned short*)ws;                      // 6.4 MB
    unsigned short* hwb2 = (unsigned short*)(ws + (size_t)7  * 1024 * 1024); // 6.4 MB
    uint2*    slab  = (uint2*)   (ws + (size_t)14 * 1024 * 1024);    // 6.4 MB
    unsigned* edges = (unsigned*)(ws + (size_t)21 * 1024 * 1024);    // 3.2 MB
    int*      start = (int*)     (ws + (size_t)25 * 1024 * 1024);    // 50001 ints
    int*      cnt   = start + N_NODES + 8;                           // NB1*NBKT
    int*      cnt_t = cnt + NB1 * NBKT;                              // NBKT*NB1

    dim3 blk(256);

    // K1: hist blocks first, then gemm1 blocks (one launch, parallel)
    gemm1_hist<<<dim3(NB1 + GG), blk, 0, stream>>>(x, w1, hwb, dst, cnt, cnt_t);
    // K2: bucket partition (self-computed offsets)
    binscatter<<<dim3(NB1), blk, 0, stream>>>(src, dst, ew, cnt, cnt_t, slab);
    // K3: per-bucket dst sort -> packed edges + start[]
    sort_bucket<<<dim3(NBKT), dim3(512), 0, stream>>>(slab, cnt_t, edges, start);
    // K4: agg1 + b1 + relu -> h (f32, staged in d_out)
    agg_relu<<<dim3(AGG_B), blk, 0, stream>>>(hwb, edges, start, b1, out);
    // K5: gemm2: h @ w2 -> bf16 hwb2
    gemm_tile<N_HID><<<dim3(GG), blk, 0, stream>>>(out, w2, hwb2);
    // K6: agg2 + b2 -> out
    agg_out<<<dim3(AGG_B), blk, 0, stream>>>(hwb2, edges, start, b2, out);
}